// Round 2
// 1298.866 us; speedup vs baseline: 1.1517x; 1.1517x over previous
//
#include <hip/hip_runtime.h>

// Problem constants (match reference setup_inputs()).
constexpr int NA    = 200000;
constexpr int NW    = 50000;
constexpr int D     = 256;
constexpr int P     = 64;
constexpr int E_TIC = 4000000;
constexpr int E_REL = 1000000;
constexpr int NCAT  = NA + NW;                         // concatenated dst space
constexpr int SCAN_CHUNK = 2048;
constexpr int NBLK  = (NCAT + SCAN_CHUNK - 1) / SCAN_CHUNK;  // 123

// Block-count constants for the fat (merged) launches.
constexpr int GEMM_A_BLOCKS = (NA + 63) / 64;          // 3125
constexpr int GEMM_W_BLOCKS = (NW + 63) / 64;          // 782
constexpr int CNT_T_BLOCKS  = (E_TIC + 1023) / 1024;   // 3907 (4 edges/thread)
constexpr int CNT_R_BLOCKS  = (E_REL + 1023) / 1024;   // 977
constexpr int FILL_T_BLOCKS = CNT_T_BLOCKS;
constexpr int FILL_R_BLOCKS = CNT_R_BLOCKS;
constexpr int FILL_BLOCKS   = FILL_T_BLOCKS + FILL_R_BLOCKS;  // 4884

// ---------------------------------------------------------------------------
// Fused multi-weight GEMM body: Y_m = X @ W_m, X:[N,256], W:[256,64].
// Device function so it can be co-scheduled with other work in a fat kernel.
// ---------------------------------------------------------------------------
template <int NM>
__device__ __forceinline__ void gemm_body(
    int bid, const float* __restrict__ x, int N,
    const float* __restrict__ W0, const float* __restrict__ W1,
    const float* __restrict__ W2,
    float* __restrict__ o0, float* __restrict__ o1, float* __restrict__ o2) {
  __shared__ float xT[32][68];
  __shared__ float Wc[NM][32][64];

  const float* Wp[3] = {W0, W1, W2};
  float* op[3] = {o0, o1, o2};

  const int tid = threadIdx.x;
  const int tx = tid & 15;
  const int ty = tid >> 4;
  const int n0 = bid * 64;

  float acc[NM][4][4];
#pragma unroll
  for (int m = 0; m < NM; ++m)
#pragma unroll
    for (int i = 0; i < 4; ++i)
#pragma unroll
      for (int j = 0; j < 4; ++j) acc[m][i][j] = 0.f;

  for (int kc = 0; kc < D / 32; ++kc) {
#pragma unroll
    for (int i = 0; i < 2; ++i) {
      int f = tid + i * 256;
      int row = f >> 3;
      int c4 = f & 7;
      int n = n0 + row;
      float4 v = make_float4(0.f, 0.f, 0.f, 0.f);
      if (n < N)
        v = *(const float4*)(x + (size_t)n * D + kc * 32 + c4 * 4);
      xT[c4 * 4 + 0][row] = v.x;
      xT[c4 * 4 + 1][row] = v.y;
      xT[c4 * 4 + 2][row] = v.z;
      xT[c4 * 4 + 3][row] = v.w;
    }
#pragma unroll
    for (int m = 0; m < NM; ++m) {
#pragma unroll
      for (int i = 0; i < 2; ++i) {
        int f = tid + i * 256;
        ((float4*)&Wc[m][0][0])[f] =
            ((const float4*)(Wp[m] + kc * 32 * 64))[f];
      }
    }
    __syncthreads();

#pragma unroll 4
    for (int d = 0; d < 32; ++d) {
      float4 a4 = *(const float4*)&xT[d][ty * 4];
      float av[4] = {a4.x, a4.y, a4.z, a4.w};
#pragma unroll
      for (int m = 0; m < NM; ++m) {
        float4 b4 = *(const float4*)&Wc[m][d][tx * 4];
        float bv[4] = {b4.x, b4.y, b4.z, b4.w};
#pragma unroll
        for (int i = 0; i < 4; ++i)
#pragma unroll
          for (int j = 0; j < 4; ++j) acc[m][i][j] += av[i] * bv[j];
      }
    }
    __syncthreads();
  }

#pragma unroll
  for (int m = 0; m < NM; ++m) {
#pragma unroll
    for (int i = 0; i < 4; ++i) {
      int n = n0 + ty * 4 + i;
      if (n < N) {
        float4 v = make_float4(acc[m][i][0], acc[m][i][1], acc[m][i][2],
                               acc[m][i][3]);
        *(float4*)(op[m] + (size_t)n * 64 + tx * 4) = v;
      }
    }
  }
}

// ---------------------------------------------------------------------------
// CSR build bodies (4 edges/thread for MLP under reduced occupancy).
// ---------------------------------------------------------------------------
__device__ __forceinline__ void count_body(const int* __restrict__ dst,
                                           int* __restrict__ deg, int E,
                                           int base, int bid) {
  int b0 = bid * 1024 + threadIdx.x;
#pragma unroll
  for (int i = 0; i < 4; ++i) {
    int e = b0 + i * 256;
    if (e < E) atomicAdd(&deg[base + dst[e]], 1);
  }
}

__device__ __forceinline__ void fill_body(
    const int* __restrict__ src, const int* __restrict__ dst,
    const float* __restrict__ w, int* __restrict__ rp,
    int2* __restrict__ edges, int E, int base, int bid) {
  int b0 = bid * 1024 + threadIdx.x;
  int dv[4], sv[4];
  float wv[4];
  bool ok[4];
#pragma unroll
  for (int i = 0; i < 4; ++i) {
    int e = b0 + i * 256;
    ok[i] = e < E;
    if (ok[i]) {
      dv[i] = dst[e];
      sv[i] = src[e];
      wv[i] = w[e];
    }
  }
  int pos[4];
#pragma unroll
  for (int i = 0; i < 4; ++i)
    if (ok[i]) pos[i] = atomicAdd(&rp[base + dv[i]], 1);
#pragma unroll
  for (int i = 0; i < 4; ++i)
    if (ok[i]) edges[pos[i]] = make_int2(sv[i], __float_as_int(wv[i]));
}

// ---------------------------------------------------------------------------
// Fat kernel A: gemm_fused<1> (word self) + both degree counts.
// Counts are atomic-latency-bound (VALU ~idle); gemm rides in the bubbles.
// ---------------------------------------------------------------------------
__global__ __launch_bounds__(256) void fatA(
    const float* __restrict__ x_w, const float* __restrict__ Wsr,
    float* __restrict__ out_w, const int* __restrict__ dst_t,
    const int* __restrict__ dst_r, int* __restrict__ deg) {
  int bid = blockIdx.x;
  if (bid < GEMM_W_BLOCKS) {
    gemm_body<1>(bid, x_w, NW, Wsr, nullptr, nullptr, out_w, nullptr, nullptr);
    return;
  }
  bid -= GEMM_W_BLOCKS;
  if (bid < CNT_T_BLOCKS) {
    count_body(dst_t, deg, E_TIC, 0, bid);
    return;
  }
  bid -= CNT_T_BLOCKS;
  count_body(dst_r, deg, E_REL, NA, bid);
}

// ---------------------------------------------------------------------------
// Fat kernel B: gemm_fused<3> (acoustic, the big GEMM) interleaved with both
// CSR fills. Fill is scatter/atomic-bound at 10% HBM with 0.4% VALUBusy;
// the GEMM's FLOPs overlap it. Interleave: even bids (< 2*NG) are gemm.
// ---------------------------------------------------------------------------
__global__ __launch_bounds__(256) void fatB(
    const float* __restrict__ x_ac, const float* __restrict__ Wst,
    const float* __restrict__ Wnt, const float* __restrict__ Wnr,
    float* __restrict__ out_ac, float* __restrict__ h_tic,
    float* __restrict__ h_relm, const int* __restrict__ src_t,
    const int* __restrict__ dst_t, const float* __restrict__ w_t,
    const int* __restrict__ src_r, const int* __restrict__ dst_r,
    const float* __restrict__ w_r, int* __restrict__ rp,
    int2* __restrict__ edges) {
  int bid = blockIdx.x;
  int fidx;
  if (bid < 2 * GEMM_A_BLOCKS) {
    if ((bid & 1) == 0) {
      gemm_body<3>(bid >> 1, x_ac, NA, Wst, Wnt, Wnr, out_ac, h_tic, h_relm);
      return;
    }
    fidx = bid >> 1;
  } else {
    fidx = bid - GEMM_A_BLOCKS;
  }
  if (fidx < FILL_T_BLOCKS)
    fill_body(src_t, dst_t, w_t, rp, edges, E_TIC, 0, fidx);
  else
    fill_body(src_r, dst_r, w_r, rp, edges, E_REL, NA, fidx - FILL_T_BLOCKS);
}

// ---------------------------------------------------------------------------
// CSR build step 2: exclusive prefix scan over deg_cat[NCAT] -> rp[NCAT].
// ---------------------------------------------------------------------------
__global__ __launch_bounds__(256) void scan_block(const int* __restrict__ deg,
                                                  int* __restrict__ rp,
                                                  int* __restrict__ bsum) {
  __shared__ int lds[256];
  int b = blockIdx.x, t = threadIdx.x;
  int base = b * SCAN_CHUNK + t * 8;
  int v[8];
#pragma unroll
  for (int j = 0; j < 8; ++j) {
    int idx = base + j;
    v[j] = (idx < NCAT) ? deg[idx] : 0;
  }
  int s = 0;
#pragma unroll
  for (int j = 0; j < 8; ++j) {
    int tmp = v[j];
    v[j] = s;          // exclusive within thread
    s += tmp;
  }
  lds[t] = s;
  __syncthreads();
  for (int off = 1; off < 256; off <<= 1) {
    int x = (t >= off) ? lds[t - off] : 0;
    __syncthreads();
    lds[t] += x;
    __syncthreads();
  }
  int excl = (t == 0) ? 0 : lds[t - 1];
  if (t == 255) bsum[b] = lds[255];
#pragma unroll
  for (int j = 0; j < 8; ++j) {
    int idx = base + j;
    if (idx < NCAT) rp[idx] = excl + v[j];
  }
}

__global__ __launch_bounds__(256) void scan_bsum(int* __restrict__ bsum) {
  __shared__ int lds[256];
  int t = threadIdx.x;
  lds[t] = (t < NBLK) ? bsum[t] : 0;
  __syncthreads();
  for (int off = 1; off < 256; off <<= 1) {
    int x = (t >= off) ? lds[t - off] : 0;
    __syncthreads();
    lds[t] += x;
    __syncthreads();
  }
  int excl = (t == 0) ? 0 : lds[t - 1];
  if (t < NBLK) bsum[t] = excl;
}

__global__ __launch_bounds__(256) void scan_add(int* __restrict__ rp,
                                                const int* __restrict__ bsum) {
  int i = blockIdx.x * 256 + threadIdx.x;
  if (i < NCAT) rp[i] += bsum[i >> 11];
}

// ---------------------------------------------------------------------------
// Fat kernel C: both pull aggregations merged. One wave per dst node; lane =
// output channel. Each edge -> one coalesced 256 B read of h[src].
//   acoustic (gw < NA): out[n] += sum/deg + b
//   word     (gw >= NA): out[n] = 0.5*(xw[n,:64] + out[n] + sum/deg + b)
// ---------------------------------------------------------------------------
__global__ __launch_bounds__(256) void pull_all(
    const float* __restrict__ h_tic, const float* __restrict__ h_relm,
    const int2* __restrict__ edges, const int* __restrict__ rp,
    const int* __restrict__ deg, const float* __restrict__ bt,
    const float* __restrict__ br, const float* __restrict__ xw,
    float* __restrict__ out_ac, float* __restrict__ out_w) {
  int gw = (blockIdx.x * 256 + threadIdx.x) >> 6;
  if (gw >= NCAT) return;
  int lane = threadIdx.x & 63;
  bool word = gw >= NA;

  int end = rp[gw];            // row end (post-fill)
  int cnt = deg[gw];
  int start = end - cnt;

  const float* h = word ? h_relm : h_tic;
  float acc = 0.f;
  for (int c = start; c < end; c += 64) {
    int2 ed = make_int2(0, 0);
    int idx = c + lane;
    if (idx < end) ed = edges[idx];
    int m = min(64, end - c);
    for (int j = 0; j < m; ++j) {
      int s = __shfl(ed.x, j);
      float wv = __int_as_float(__shfl(ed.y, j));
      acc += h[(size_t)s * 64 + lane] * wv;
    }
  }
  float neigh = cnt > 0 ? acc / (float)cnt : 0.f;
  if (!word) {
    size_t oi = (size_t)gw * 64 + lane;
    out_ac[oi] += neigh + bt[lane];
  } else {
    int n = gw - NA;
    size_t oi = (size_t)n * 64 + lane;
    out_w[oi] = 0.5f * (xw[(size_t)n * D + lane] + out_w[oi] + neigh + br[lane]);
  }
}

extern "C" void kernel_launch(void* const* d_in, const int* in_sizes, int n_in,
                              void* d_out, int out_size, void* d_ws,
                              size_t ws_size, hipStream_t stream) {
  const float* x_ac  = (const float*)d_in[0];
  const float* x_w   = (const float*)d_in[1];
  const int*   src_t = (const int*)d_in[2];
  const int*   dst_t = (const int*)d_in[3];
  const float* w_t   = (const float*)d_in[4];
  const int*   src_r = (const int*)d_in[5];
  const int*   dst_r = (const int*)d_in[6];
  const float* w_r   = (const float*)d_in[7];
  const float* Wst   = (const float*)d_in[8];
  const float* Wnt   = (const float*)d_in[9];
  const float* bt    = (const float*)d_in[10];
  const float* Wsr   = (const float*)d_in[11];
  const float* Wnr   = (const float*)d_in[12];
  const float* br    = (const float*)d_in[13];

  float* out_ac = (float*)d_out;                      // [NA,64]
  float* out_w  = (float*)d_out + (size_t)NA * 64;    // [NW,64]

  // Workspace layout.
  float* ws     = (float*)d_ws;
  float* h_tic  = ws;                                 // NA*64 floats
  float* h_relm = h_tic + (size_t)NA * 64;            // NA*64 floats
  int2*  edges  = (int2*)(h_relm + (size_t)NA * 64);  // (E_TIC+E_REL) int2
  int*   deg    = (int*)(edges + (size_t)(E_TIC + E_REL));  // NCAT ints
  int*   rp     = deg + NCAT;                         // NCAT ints
  int*   bsum   = rp + NCAT;                          // NBLK ints

  hipMemsetAsync(deg, 0, (size_t)NCAT * 4, stream);

  // L1: word self-GEMM + both degree counts (independent, co-scheduled).
  fatA<<<GEMM_W_BLOCKS + CNT_T_BLOCKS + CNT_R_BLOCKS, 256, 0, stream>>>(
      x_w, Wsr, out_w, dst_t, dst_r, deg);

  // L2: prefix scan deg -> rp (row starts).
  scan_block<<<NBLK, 256, 0, stream>>>(deg, rp, bsum);
  scan_bsum<<<1, 256, 0, stream>>>(bsum);
  scan_add<<<(NCAT + 255) / 256, 256, 0, stream>>>(rp, bsum);

  // L3: big acoustic GEMM (3 weight mats) interleaved with both CSR fills.
  fatB<<<GEMM_A_BLOCKS + FILL_BLOCKS, 256, 0, stream>>>(
      x_ac, Wst, Wnt, Wnr, out_ac, h_tic, h_relm,
      src_t, dst_t, w_t, src_r, dst_r, w_r, rp, edges);

  // L4: both pull aggregations + fused epilogues.
  pull_all<<<(NCAT * 64 + 255) / 256, 256, 0, stream>>>(
      h_tic, h_relm, edges, rp, deg, bt, br, x_w, out_ac, out_w);
}

// Round 3
// 1151.233 us; speedup vs baseline: 1.2994x; 1.1282x over previous
//
#include <hip/hip_runtime.h>

// Problem constants (match reference setup_inputs()).
constexpr int NA    = 200000;
constexpr int NW    = 50000;
constexpr int D     = 256;
constexpr int P     = 64;
constexpr int E_TIC = 4000000;
constexpr int E_REL = 1000000;
constexpr int NCAT  = NA + NW;                         // concatenated dst space
constexpr int SCAN_CHUNK = 2048;
constexpr int NBLK  = (NCAT + SCAN_CHUNK - 1) / SCAN_CHUNK;  // 123
constexpr int KC    = 16;                              // gemm K-chunk (LDS size!)

// Block-count constants for the fat (merged) launches.
constexpr int GEMM_A_BLOCKS = (NA + 63) / 64;          // 3125
constexpr int GEMM_W_BLOCKS = (NW + 63) / 64;          // 782
constexpr int CNT_T_BLOCKS  = (E_TIC + 1023) / 1024;   // 3907 (4 edges/thread)
constexpr int CNT_R_BLOCKS  = (E_REL + 1023) / 1024;   // 977
constexpr int FILL_T_BLOCKS = CNT_T_BLOCKS;
constexpr int FILL_R_BLOCKS = CNT_R_BLOCKS;
constexpr int FILL_BLOCKS   = FILL_T_BLOCKS + FILL_R_BLOCKS;  // 4884

// ---------------------------------------------------------------------------
// Fused multi-weight GEMM body: Y_m = X @ W_m, X:[N,256], W:[256,64].
// K-chunk = 16 so LDS (NM=3) = 16640 B -> 8 blocks/CU in the fat kernel;
// fill blocks in the same kernel get the occupancy for latency hiding.
// ---------------------------------------------------------------------------
template <int NM>
__device__ __forceinline__ void gemm_body(
    int bid, const float* __restrict__ x, int N,
    const float* __restrict__ W0, const float* __restrict__ W1,
    const float* __restrict__ W2,
    float* __restrict__ o0, float* __restrict__ o1, float* __restrict__ o2) {
  __shared__ float xT[KC][68];
  __shared__ float Wc[NM][KC][64];

  const float* Wp[3] = {W0, W1, W2};
  float* op[3] = {o0, o1, o2};

  const int tid = threadIdx.x;
  const int tx = tid & 15;
  const int ty = tid >> 4;
  const int n0 = bid * 64;

  float acc[NM][4][4];
#pragma unroll
  for (int m = 0; m < NM; ++m)
#pragma unroll
    for (int i = 0; i < 4; ++i)
#pragma unroll
      for (int j = 0; j < 4; ++j) acc[m][i][j] = 0.f;

  for (int kc = 0; kc < D / KC; ++kc) {
    {
      // 64 rows x 16 d per chunk: one float4 per thread, stored transposed.
      int row = tid >> 2;                       // 0..63
      int c4 = tid & 3;                         // 0..3
      int n = n0 + row;
      float4 v = make_float4(0.f, 0.f, 0.f, 0.f);
      if (n < N)
        v = *(const float4*)(x + (size_t)n * D + kc * KC + c4 * 4);
      xT[c4 * 4 + 0][row] = v.x;
      xT[c4 * 4 + 1][row] = v.y;
      xT[c4 * 4 + 2][row] = v.z;
      xT[c4 * 4 + 3][row] = v.w;
    }
#pragma unroll
    for (int m = 0; m < NM; ++m) {
      // KC*64 = 1024 floats = 256 float4: one per thread.
      ((float4*)&Wc[m][0][0])[tid] = ((const float4*)(Wp[m] + kc * KC * 64))[tid];
    }
    __syncthreads();

#pragma unroll 4
    for (int d = 0; d < KC; ++d) {
      float4 a4 = *(const float4*)&xT[d][ty * 4];
      float av[4] = {a4.x, a4.y, a4.z, a4.w};
#pragma unroll
      for (int m = 0; m < NM; ++m) {
        float4 b4 = *(const float4*)&Wc[m][d][tx * 4];
        float bv[4] = {b4.x, b4.y, b4.z, b4.w};
#pragma unroll
        for (int i = 0; i < 4; ++i)
#pragma unroll
          for (int j = 0; j < 4; ++j) acc[m][i][j] += av[i] * bv[j];
      }
    }
    __syncthreads();
  }

#pragma unroll
  for (int m = 0; m < NM; ++m) {
#pragma unroll
    for (int i = 0; i < 4; ++i) {
      int n = n0 + ty * 4 + i;
      if (n < N) {
        float4 v = make_float4(acc[m][i][0], acc[m][i][1], acc[m][i][2],
                               acc[m][i][3]);
        *(float4*)(op[m] + (size_t)n * 64 + tx * 4) = v;
      }
    }
  }
}

// ---------------------------------------------------------------------------
// CSR build bodies (4 edges/thread for MLP under reduced occupancy).
// ---------------------------------------------------------------------------
__device__ __forceinline__ void count_body(const int* __restrict__ dst,
                                           int* __restrict__ deg, int E,
                                           int base, int bid) {
  int b0 = bid * 1024 + threadIdx.x;
#pragma unroll
  for (int i = 0; i < 4; ++i) {
    int e = b0 + i * 256;
    if (e < E) atomicAdd(&deg[base + dst[e]], 1);
  }
}

__device__ __forceinline__ void fill_body(
    const int* __restrict__ src, const int* __restrict__ dst,
    const float* __restrict__ w, int* __restrict__ rp,
    int2* __restrict__ edges, int E, int base, int bid) {
  int b0 = bid * 1024 + threadIdx.x;
  int dv[4], sv[4];
  float wv[4];
  bool ok[4];
#pragma unroll
  for (int i = 0; i < 4; ++i) {
    int e = b0 + i * 256;
    ok[i] = e < E;
    if (ok[i]) {
      dv[i] = dst[e];
      sv[i] = src[e];
      wv[i] = w[e];
    }
  }
  int pos[4];
#pragma unroll
  for (int i = 0; i < 4; ++i)
    if (ok[i]) pos[i] = atomicAdd(&rp[base + dv[i]], 1);
#pragma unroll
  for (int i = 0; i < 4; ++i)
    if (ok[i]) edges[pos[i]] = make_int2(sv[i], __float_as_int(wv[i]));
}

// ---------------------------------------------------------------------------
// Fat kernel A: gemm_fused<1> (word self) + both degree counts.
// ---------------------------------------------------------------------------
__global__ __launch_bounds__(256) void fatA(
    const float* __restrict__ x_w, const float* __restrict__ Wsr,
    float* __restrict__ out_w, const int* __restrict__ dst_t,
    const int* __restrict__ dst_r, int* __restrict__ deg) {
  int bid = blockIdx.x;
  if (bid < GEMM_W_BLOCKS) {
    gemm_body<1>(bid, x_w, NW, Wsr, nullptr, nullptr, out_w, nullptr, nullptr);
    return;
  }
  bid -= GEMM_W_BLOCKS;
  if (bid < CNT_T_BLOCKS) {
    count_body(dst_t, deg, E_TIC, 0, bid);
    return;
  }
  bid -= CNT_T_BLOCKS;
  count_body(dst_r, deg, E_REL, NA, bid);
}

// ---------------------------------------------------------------------------
// Fat kernel B: gemm_fused<3> (acoustic) interleaved with both CSR fills.
// LDS now 16640 B -> 8 blocks/CU; fill latency hiding doubles.
// ---------------------------------------------------------------------------
__global__ __launch_bounds__(256) void fatB(
    const float* __restrict__ x_ac, const float* __restrict__ Wst,
    const float* __restrict__ Wnt, const float* __restrict__ Wnr,
    float* __restrict__ out_ac, float* __restrict__ h_tic,
    float* __restrict__ h_relm, const int* __restrict__ src_t,
    const int* __restrict__ dst_t, const float* __restrict__ w_t,
    const int* __restrict__ src_r, const int* __restrict__ dst_r,
    const float* __restrict__ w_r, int* __restrict__ rp,
    int2* __restrict__ edges) {
  int bid = blockIdx.x;
  int fidx;
  if (bid < 2 * GEMM_A_BLOCKS) {
    if ((bid & 1) == 0) {
      gemm_body<3>(bid >> 1, x_ac, NA, Wst, Wnt, Wnr, out_ac, h_tic, h_relm);
      return;
    }
    fidx = bid >> 1;
  } else {
    fidx = bid - GEMM_A_BLOCKS;
  }
  if (fidx < FILL_T_BLOCKS)
    fill_body(src_t, dst_t, w_t, rp, edges, E_TIC, 0, fidx);
  else
    fill_body(src_r, dst_r, w_r, rp, edges, E_REL, NA, fidx - FILL_T_BLOCKS);
}

// ---------------------------------------------------------------------------
// CSR build step 2: exclusive prefix scan over deg_cat[NCAT] -> rp[NCAT].
// ---------------------------------------------------------------------------
__global__ __launch_bounds__(256) void scan_block(const int* __restrict__ deg,
                                                  int* __restrict__ rp,
                                                  int* __restrict__ bsum) {
  __shared__ int lds[256];
  int b = blockIdx.x, t = threadIdx.x;
  int base = b * SCAN_CHUNK + t * 8;
  int v[8];
#pragma unroll
  for (int j = 0; j < 8; ++j) {
    int idx = base + j;
    v[j] = (idx < NCAT) ? deg[idx] : 0;
  }
  int s = 0;
#pragma unroll
  for (int j = 0; j < 8; ++j) {
    int tmp = v[j];
    v[j] = s;          // exclusive within thread
    s += tmp;
  }
  lds[t] = s;
  __syncthreads();
  for (int off = 1; off < 256; off <<= 1) {
    int x = (t >= off) ? lds[t - off] : 0;
    __syncthreads();
    lds[t] += x;
    __syncthreads();
  }
  int excl = (t == 0) ? 0 : lds[t - 1];
  if (t == 255) bsum[b] = lds[255];
#pragma unroll
  for (int j = 0; j < 8; ++j) {
    int idx = base + j;
    if (idx < NCAT) rp[idx] = excl + v[j];
  }
}

__global__ __launch_bounds__(256) void scan_bsum(int* __restrict__ bsum) {
  __shared__ int lds[256];
  int t = threadIdx.x;
  lds[t] = (t < NBLK) ? bsum[t] : 0;
  __syncthreads();
  for (int off = 1; off < 256; off <<= 1) {
    int x = (t >= off) ? lds[t - off] : 0;
    __syncthreads();
    lds[t] += x;
    __syncthreads();
  }
  int excl = (t == 0) ? 0 : lds[t - 1];
  if (t < NBLK) bsum[t] = excl;
}

__global__ __launch_bounds__(256) void scan_add(int* __restrict__ rp,
                                                const int* __restrict__ bsum) {
  int i = blockIdx.x * 256 + threadIdx.x;
  if (i < NCAT) rp[i] += bsum[i >> 11];
}

// ---------------------------------------------------------------------------
// Fat kernel C: both pull aggregations merged. One wave per dst node; lane =
// output channel. Inner loop 4-way unrolled: 4 independent 256 B gathers in
// flight per wave (was 1) to cover L3/HBM latency. FP add order identical to
// the scalar loop (j, j+1, j+2, j+3) -> bitwise same result.
// ---------------------------------------------------------------------------
__global__ __launch_bounds__(256) void pull_all(
    const float* __restrict__ h_tic, const float* __restrict__ h_relm,
    const int2* __restrict__ edges, const int* __restrict__ rp,
    const int* __restrict__ deg, const float* __restrict__ bt,
    const float* __restrict__ br, const float* __restrict__ xw,
    float* __restrict__ out_ac, float* __restrict__ out_w) {
  int gw = (blockIdx.x * 256 + threadIdx.x) >> 6;
  if (gw >= NCAT) return;
  int lane = threadIdx.x & 63;
  bool word = gw >= NA;

  int end = rp[gw];            // row end (post-fill)
  int cnt = deg[gw];
  int start = end - cnt;

  const float* h = word ? h_relm : h_tic;
  float acc = 0.f;
  for (int c = start; c < end; c += 64) {
    int idx = c + lane;
    int2 ed = (idx < end) ? edges[idx] : make_int2(0, 0);
    int m = min(64, end - c);
    int j = 0;
    for (; j + 4 <= m; j += 4) {
      int s0 = __shfl(ed.x, j + 0);
      int s1 = __shfl(ed.x, j + 1);
      int s2 = __shfl(ed.x, j + 2);
      int s3 = __shfl(ed.x, j + 3);
      float w0 = __int_as_float(__shfl(ed.y, j + 0));
      float w1 = __int_as_float(__shfl(ed.y, j + 1));
      float w2 = __int_as_float(__shfl(ed.y, j + 2));
      float w3 = __int_as_float(__shfl(ed.y, j + 3));
      float h0 = h[(size_t)s0 * 64 + lane];
      float h1 = h[(size_t)s1 * 64 + lane];
      float h2 = h[(size_t)s2 * 64 + lane];
      float h3 = h[(size_t)s3 * 64 + lane];
      acc += h0 * w0;
      acc += h1 * w1;
      acc += h2 * w2;
      acc += h3 * w3;
    }
    for (; j < m; ++j) {
      int s = __shfl(ed.x, j);
      float wv = __int_as_float(__shfl(ed.y, j));
      acc += h[(size_t)s * 64 + lane] * wv;
    }
  }
  float neigh = cnt > 0 ? acc / (float)cnt : 0.f;
  if (!word) {
    size_t oi = (size_t)gw * 64 + lane;
    out_ac[oi] += neigh + bt[lane];
  } else {
    int n = gw - NA;
    size_t oi = (size_t)n * 64 + lane;
    out_w[oi] = 0.5f * (xw[(size_t)n * D + lane] + out_w[oi] + neigh + br[lane]);
  }
}

extern "C" void kernel_launch(void* const* d_in, const int* in_sizes, int n_in,
                              void* d_out, int out_size, void* d_ws,
                              size_t ws_size, hipStream_t stream) {
  const float* x_ac  = (const float*)d_in[0];
  const float* x_w   = (const float*)d_in[1];
  const int*   src_t = (const int*)d_in[2];
  const int*   dst_t = (const int*)d_in[3];
  const float* w_t   = (const float*)d_in[4];
  const int*   src_r = (const int*)d_in[5];
  const int*   dst_r = (const int*)d_in[6];
  const float* w_r   = (const float*)d_in[7];
  const float* Wst   = (const float*)d_in[8];
  const float* Wnt   = (const float*)d_in[9];
  const float* bt    = (const float*)d_in[10];
  const float* Wsr   = (const float*)d_in[11];
  const float* Wnr   = (const float*)d_in[12];
  const float* br    = (const float*)d_in[13];

  float* out_ac = (float*)d_out;                      // [NA,64]
  float* out_w  = (float*)d_out + (size_t)NA * 64;    // [NW,64]

  // Workspace layout.
  float* ws     = (float*)d_ws;
  float* h_tic  = ws;                                 // NA*64 floats
  float* h_relm = h_tic + (size_t)NA * 64;            // NA*64 floats
  int2*  edges  = (int2*)(h_relm + (size_t)NA * 64);  // (E_TIC+E_REL) int2
  int*   deg    = (int*)(edges + (size_t)(E_TIC + E_REL));  // NCAT ints
  int*   rp     = deg + NCAT;                         // NCAT ints
  int*   bsum   = rp + NCAT;                          // NBLK ints

  hipMemsetAsync(deg, 0, (size_t)NCAT * 4, stream);

  // L1: word self-GEMM + both degree counts (independent, co-scheduled).
  fatA<<<GEMM_W_BLOCKS + CNT_T_BLOCKS + CNT_R_BLOCKS, 256, 0, stream>>>(
      x_w, Wsr, out_w, dst_t, dst_r, deg);

  // L2: prefix scan deg -> rp (row starts).
  scan_block<<<NBLK, 256, 0, stream>>>(deg, rp, bsum);
  scan_bsum<<<1, 256, 0, stream>>>(bsum);
  scan_add<<<(NCAT + 255) / 256, 256, 0, stream>>>(rp, bsum);

  // L3: big acoustic GEMM (3 weight mats) interleaved with both CSR fills.
  fatB<<<GEMM_A_BLOCKS + FILL_BLOCKS, 256, 0, stream>>>(
      x_ac, Wst, Wnt, Wnr, out_ac, h_tic, h_relm,
      src_t, dst_t, w_t, src_r, dst_r, w_r, rp, edges);

  // L4: both pull aggregations + fused epilogues.
  pull_all<<<(NCAT * 64 + 255) / 256, 256, 0, stream>>>(
      h_tic, h_relm, edges, rp, deg, bt, br, x_w, out_ac, out_w);
}

// Round 4
// 1096.565 us; speedup vs baseline: 1.3642x; 1.0499x over previous
//
#include <hip/hip_runtime.h>

// Problem constants (match reference setup_inputs()).
constexpr int NA    = 200000;
constexpr int NW    = 50000;
constexpr int D     = 256;
constexpr int P     = 64;
constexpr int E_TIC = 4000000;
constexpr int E_REL = 1000000;
constexpr int NCAT  = NA + NW;                         // concatenated dst space
constexpr int SCAN_CHUNK = 2048;
constexpr int NBLK  = (NCAT + SCAN_CHUNK - 1) / SCAN_CHUNK;  // 123
constexpr int KC    = 16;                              // gemm K-chunk (LDS size!)

// Block-count constants for the fat (merged) launches.
constexpr int GEMM_A_BLOCKS = (NA + 63) / 64;          // 3125
constexpr int GEMM_W_BLOCKS = (NW + 63) / 64;          // 782
constexpr int CNT_T_BLOCKS  = (E_TIC + 1023) / 1024;   // 3907 (4 edges/thread)
constexpr int CNT_R_BLOCKS  = (E_REL + 1023) / 1024;   // 977
constexpr int FILL_T_BLOCKS = (E_TIC + 2047) / 2048;   // 1954 (8 edges/thread)
constexpr int FILL_R_BLOCKS = (E_REL + 2047) / 2048;   // 489
constexpr int FILL_BLOCKS   = FILL_T_BLOCKS + FILL_R_BLOCKS;  // 2443

constexpr int TOT_A = GEMM_W_BLOCKS + CNT_T_BLOCKS + CNT_R_BLOCKS;  // 5666
constexpr int TOT_B = GEMM_A_BLOCKS + FILL_BLOCKS;                  // 5568

// Nontemporal helpers (cache hints only; no semantic change).
typedef float v4f __attribute__((ext_vector_type(4)));
typedef int   v2i __attribute__((ext_vector_type(2)));

static __device__ __forceinline__ v4f nt_load4(const float* p) {
  return __builtin_nontemporal_load((const v4f*)p);
}
static __device__ __forceinline__ void nt_store4(float* p, v4f v) {
  __builtin_nontemporal_store(v, (v4f*)p);
}

// ---------------------------------------------------------------------------
// Fused multi-weight GEMM body: Y_m = X @ W_m, X:[N,256], W:[256,64].
// K-chunk = 16 -> LDS (NM=3) = 16896 B. x streamed with nt loads (read-once);
// outputs streamed with nt stores; W kept cacheable (tiny, reused globally).
// ---------------------------------------------------------------------------
template <int NM>
__device__ __forceinline__ void gemm_body(
    int bid, const float* __restrict__ x, int N,
    const float* __restrict__ W0, const float* __restrict__ W1,
    const float* __restrict__ W2,
    float* __restrict__ o0, float* __restrict__ o1, float* __restrict__ o2) {
  __shared__ float xT[KC][68];
  __shared__ float Wc[NM][KC][64];

  const float* Wp[3] = {W0, W1, W2};
  float* op[3] = {o0, o1, o2};

  const int tid = threadIdx.x;
  const int tx = tid & 15;
  const int ty = tid >> 4;
  const int n0 = bid * 64;

  float acc[NM][4][4];
#pragma unroll
  for (int m = 0; m < NM; ++m)
#pragma unroll
    for (int i = 0; i < 4; ++i)
#pragma unroll
      for (int j = 0; j < 4; ++j) acc[m][i][j] = 0.f;

  for (int kc = 0; kc < D / KC; ++kc) {
    {
      // 64 rows x 16 d per chunk: one float4 per thread, stored transposed.
      int row = tid >> 2;                       // 0..63
      int c4 = tid & 3;                         // 0..3
      int n = n0 + row;
      v4f v = 0;
      if (n < N) v = nt_load4(x + (size_t)n * D + kc * KC + c4 * 4);
      xT[c4 * 4 + 0][row] = v.x;
      xT[c4 * 4 + 1][row] = v.y;
      xT[c4 * 4 + 2][row] = v.z;
      xT[c4 * 4 + 3][row] = v.w;
    }
#pragma unroll
    for (int m = 0; m < NM; ++m) {
      // KC*64 = 1024 floats = 256 float4: one per thread.
      ((float4*)&Wc[m][0][0])[tid] = ((const float4*)(Wp[m] + kc * KC * 64))[tid];
    }
    __syncthreads();

#pragma unroll 4
    for (int d = 0; d < KC; ++d) {
      float4 a4 = *(const float4*)&xT[d][ty * 4];
      float av[4] = {a4.x, a4.y, a4.z, a4.w};
#pragma unroll
      for (int m = 0; m < NM; ++m) {
        float4 b4 = *(const float4*)&Wc[m][d][tx * 4];
        float bv[4] = {b4.x, b4.y, b4.z, b4.w};
#pragma unroll
        for (int i = 0; i < 4; ++i)
#pragma unroll
          for (int j = 0; j < 4; ++j) acc[m][i][j] += av[i] * bv[j];
      }
    }
    __syncthreads();
  }

#pragma unroll
  for (int m = 0; m < NM; ++m) {
#pragma unroll
    for (int i = 0; i < 4; ++i) {
      int n = n0 + ty * 4 + i;
      if (n < N) {
        v4f v;
        v.x = acc[m][i][0]; v.y = acc[m][i][1];
        v.z = acc[m][i][2]; v.w = acc[m][i][3];
        nt_store4(op[m] + (size_t)n * 64 + tx * 4, v);
      }
    }
  }
}

// ---------------------------------------------------------------------------
// CSR build bodies. count: 4 edges/thread; fill: 8 edges/thread (scatter is
// latency-bound -> maximize in-flight per wave). nt on read-once streams and
// on the random 8 B scatter (avoid L2 pollution of the co-resident gemm).
// ---------------------------------------------------------------------------
__device__ __forceinline__ void count_body(const int* __restrict__ dst,
                                           int* __restrict__ deg, int E,
                                           int base, int bid) {
  int b0 = bid * 1024 + threadIdx.x;
#pragma unroll
  for (int i = 0; i < 4; ++i) {
    int e = b0 + i * 256;
    if (e < E) atomicAdd(&deg[base + __builtin_nontemporal_load(&dst[e])], 1);
  }
}

__device__ __forceinline__ void fill_body(
    const int* __restrict__ src, const int* __restrict__ dst,
    const float* __restrict__ w, int* __restrict__ rp,
    int2* __restrict__ edges, int E, int base, int bid) {
  int b0 = bid * 2048 + threadIdx.x;
  int dv[8], sv[8];
  float wv[8];
  bool ok[8];
#pragma unroll
  for (int i = 0; i < 8; ++i) {
    int e = b0 + i * 256;
    ok[i] = e < E;
    if (ok[i]) {
      dv[i] = __builtin_nontemporal_load(&dst[e]);
      sv[i] = __builtin_nontemporal_load(&src[e]);
      wv[i] = __builtin_nontemporal_load(&w[e]);
    }
  }
  int pos[8];
#pragma unroll
  for (int i = 0; i < 8; ++i)
    if (ok[i]) pos[i] = atomicAdd(&rp[base + dv[i]], 1);
#pragma unroll
  for (int i = 0; i < 8; ++i)
    if (ok[i]) {
      v2i rec;
      rec.x = sv[i];
      rec.y = __float_as_int(wv[i]);
      __builtin_nontemporal_store(rec, (v2i*)&edges[pos[i]]);
    }
}

// ---------------------------------------------------------------------------
// Fat kernel A: gemm_fused<1> (word self) + both degree counts, with gemm
// blocks Bresenham-spread across the grid (overlap over full duration).
// ---------------------------------------------------------------------------
__global__ __launch_bounds__(256) void fatA(
    const float* __restrict__ x_w, const float* __restrict__ Wsr,
    float* __restrict__ out_w, const int* __restrict__ dst_t,
    const int* __restrict__ dst_r, int* __restrict__ deg) {
  int bid = blockIdx.x;
  int gb = (int)(((long long)bid * GEMM_W_BLOCKS) / TOT_A);
  int ga = (int)(((long long)(bid + 1) * GEMM_W_BLOCKS) / TOT_A);
  if (ga > gb) {
    gemm_body<1>(gb, x_w, NW, Wsr, nullptr, nullptr, out_w, nullptr, nullptr);
    return;
  }
  int fidx = bid - gb;
  if (fidx < CNT_T_BLOCKS) {
    count_body(dst_t, deg, E_TIC, 0, fidx);
    return;
  }
  count_body(dst_r, deg, E_REL, NA, fidx - CNT_T_BLOCKS);
}

// ---------------------------------------------------------------------------
// Fat kernel B: gemm_fused<3> (acoustic) + both CSR fills, gemm blocks
// Bresenham-spread so no pure-fill (unoverlapped) tail remains.
// ---------------------------------------------------------------------------
__global__ __launch_bounds__(256) void fatB(
    const float* __restrict__ x_ac, const float* __restrict__ Wst,
    const float* __restrict__ Wnt, const float* __restrict__ Wnr,
    float* __restrict__ out_ac, float* __restrict__ h_tic,
    float* __restrict__ h_relm, const int* __restrict__ src_t,
    const int* __restrict__ dst_t, const float* __restrict__ w_t,
    const int* __restrict__ src_r, const int* __restrict__ dst_r,
    const float* __restrict__ w_r, int* __restrict__ rp,
    int2* __restrict__ edges) {
  int bid = blockIdx.x;
  int gb = (int)(((long long)bid * GEMM_A_BLOCKS) / TOT_B);
  int ga = (int)(((long long)(bid + 1) * GEMM_A_BLOCKS) / TOT_B);
  if (ga > gb) {
    gemm_body<3>(gb, x_ac, NA, Wst, Wnt, Wnr, out_ac, h_tic, h_relm);
    return;
  }
  int fidx = bid - gb;
  if (fidx < FILL_T_BLOCKS)
    fill_body(src_t, dst_t, w_t, rp, edges, E_TIC, 0, fidx);
  else
    fill_body(src_r, dst_r, w_r, rp, edges, E_REL, NA, fidx - FILL_T_BLOCKS);
}

// ---------------------------------------------------------------------------
// CSR build step 2: exclusive prefix scan over deg_cat[NCAT] -> rp[NCAT].
// ---------------------------------------------------------------------------
__global__ __launch_bounds__(256) void scan_block(const int* __restrict__ deg,
                                                  int* __restrict__ rp,
                                                  int* __restrict__ bsum) {
  __shared__ int lds[256];
  int b = blockIdx.x, t = threadIdx.x;
  int base = b * SCAN_CHUNK + t * 8;
  int v[8];
#pragma unroll
  for (int j = 0; j < 8; ++j) {
    int idx = base + j;
    v[j] = (idx < NCAT) ? deg[idx] : 0;
  }
  int s = 0;
#pragma unroll
  for (int j = 0; j < 8; ++j) {
    int tmp = v[j];
    v[j] = s;          // exclusive within thread
    s += tmp;
  }
  lds[t] = s;
  __syncthreads();
  for (int off = 1; off < 256; off <<= 1) {
    int x = (t >= off) ? lds[t - off] : 0;
    __syncthreads();
    lds[t] += x;
    __syncthreads();
  }
  int excl = (t == 0) ? 0 : lds[t - 1];
  if (t == 255) bsum[b] = lds[255];
#pragma unroll
  for (int j = 0; j < 8; ++j) {
    int idx = base + j;
    if (idx < NCAT) rp[idx] = excl + v[j];
  }
}

__global__ __launch_bounds__(256) void scan_bsum(int* __restrict__ bsum) {
  __shared__ int lds[256];
  int t = threadIdx.x;
  lds[t] = (t < NBLK) ? bsum[t] : 0;
  __syncthreads();
  for (int off = 1; off < 256; off <<= 1) {
    int x = (t >= off) ? lds[t - off] : 0;
    __syncthreads();
    lds[t] += x;
    __syncthreads();
  }
  int excl = (t == 0) ? 0 : lds[t - 1];
  if (t < NBLK) bsum[t] = excl;
}

__global__ __launch_bounds__(256) void scan_add(int* __restrict__ rp,
                                                const int* __restrict__ bsum) {
  int i = blockIdx.x * 256 + threadIdx.x;
  if (i < NCAT) rp[i] += bsum[i >> 11];
}

// ---------------------------------------------------------------------------
// Fat kernel C: both pull aggregations merged. One wave per dst node; lane =
// output channel. Inner loop 8-way unrolled: 8 independent 256 B gathers in
// flight per wave. FP add order identical to the scalar loop (sequential j)
// -> bitwise same result.
// ---------------------------------------------------------------------------
__global__ __launch_bounds__(256) void pull_all(
    const float* __restrict__ h_tic, const float* __restrict__ h_relm,
    const int2* __restrict__ edges, const int* __restrict__ rp,
    const int* __restrict__ deg, const float* __restrict__ bt,
    const float* __restrict__ br, const float* __restrict__ xw,
    float* __restrict__ out_ac, float* __restrict__ out_w) {
  int gw = (blockIdx.x * 256 + threadIdx.x) >> 6;
  if (gw >= NCAT) return;
  int lane = threadIdx.x & 63;
  bool word = gw >= NA;

  int end = rp[gw];            // row end (post-fill)
  int cnt = deg[gw];
  int start = end - cnt;

  const float* h = word ? h_relm : h_tic;
  float acc = 0.f;
  for (int c = start; c < end; c += 64) {
    int idx = c + lane;
    v2i ed = 0;
    if (idx < end) ed = __builtin_nontemporal_load((const v2i*)&edges[idx]);
    int m = min(64, end - c);
    int j = 0;
    for (; j + 8 <= m; j += 8) {
      int s0 = __shfl(ed.x, j + 0);
      int s1 = __shfl(ed.x, j + 1);
      int s2 = __shfl(ed.x, j + 2);
      int s3 = __shfl(ed.x, j + 3);
      int s4 = __shfl(ed.x, j + 4);
      int s5 = __shfl(ed.x, j + 5);
      int s6 = __shfl(ed.x, j + 6);
      int s7 = __shfl(ed.x, j + 7);
      float w0 = __int_as_float(__shfl(ed.y, j + 0));
      float w1 = __int_as_float(__shfl(ed.y, j + 1));
      float w2 = __int_as_float(__shfl(ed.y, j + 2));
      float w3 = __int_as_float(__shfl(ed.y, j + 3));
      float w4 = __int_as_float(__shfl(ed.y, j + 4));
      float w5 = __int_as_float(__shfl(ed.y, j + 5));
      float w6 = __int_as_float(__shfl(ed.y, j + 6));
      float w7 = __int_as_float(__shfl(ed.y, j + 7));
      float h0 = h[(size_t)s0 * 64 + lane];
      float h1 = h[(size_t)s1 * 64 + lane];
      float h2 = h[(size_t)s2 * 64 + lane];
      float h3 = h[(size_t)s3 * 64 + lane];
      float h4 = h[(size_t)s4 * 64 + lane];
      float h5 = h[(size_t)s5 * 64 + lane];
      float h6 = h[(size_t)s6 * 64 + lane];
      float h7 = h[(size_t)s7 * 64 + lane];
      acc += h0 * w0;
      acc += h1 * w1;
      acc += h2 * w2;
      acc += h3 * w3;
      acc += h4 * w4;
      acc += h5 * w5;
      acc += h6 * w6;
      acc += h7 * w7;
    }
    for (; j + 4 <= m; j += 4) {
      int s0 = __shfl(ed.x, j + 0);
      int s1 = __shfl(ed.x, j + 1);
      int s2 = __shfl(ed.x, j + 2);
      int s3 = __shfl(ed.x, j + 3);
      float w0 = __int_as_float(__shfl(ed.y, j + 0));
      float w1 = __int_as_float(__shfl(ed.y, j + 1));
      float w2 = __int_as_float(__shfl(ed.y, j + 2));
      float w3 = __int_as_float(__shfl(ed.y, j + 3));
      float h0 = h[(size_t)s0 * 64 + lane];
      float h1 = h[(size_t)s1 * 64 + lane];
      float h2 = h[(size_t)s2 * 64 + lane];
      float h3 = h[(size_t)s3 * 64 + lane];
      acc += h0 * w0;
      acc += h1 * w1;
      acc += h2 * w2;
      acc += h3 * w3;
    }
    for (; j < m; ++j) {
      int s = __shfl(ed.x, j);
      float wv = __int_as_float(__shfl(ed.y, j));
      acc += h[(size_t)s * 64 + lane] * wv;
    }
  }
  float neigh = cnt > 0 ? acc / (float)cnt : 0.f;
  if (!word) {
    size_t oi = (size_t)gw * 64 + lane;
    out_ac[oi] += neigh + bt[lane];
  } else {
    int n = gw - NA;
    size_t oi = (size_t)n * 64 + lane;
    float xv = __builtin_nontemporal_load(&xw[(size_t)n * D + lane]);
    out_w[oi] = 0.5f * (xv + out_w[oi] + neigh + br[lane]);
  }
}

extern "C" void kernel_launch(void* const* d_in, const int* in_sizes, int n_in,
                              void* d_out, int out_size, void* d_ws,
                              size_t ws_size, hipStream_t stream) {
  const float* x_ac  = (const float*)d_in[0];
  const float* x_w   = (const float*)d_in[1];
  const int*   src_t = (const int*)d_in[2];
  const int*   dst_t = (const int*)d_in[3];
  const float* w_t   = (const float*)d_in[4];
  const int*   src_r = (const int*)d_in[5];
  const int*   dst_r = (const int*)d_in[6];
  const float* w_r   = (const float*)d_in[7];
  const float* Wst   = (const float*)d_in[8];
  const float* Wnt   = (const float*)d_in[9];
  const float* bt    = (const float*)d_in[10];
  const float* Wsr   = (const float*)d_in[11];
  const float* Wnr   = (const float*)d_in[12];
  const float* br    = (const float*)d_in[13];

  float* out_ac = (float*)d_out;                      // [NA,64]
  float* out_w  = (float*)d_out + (size_t)NA * 64;    // [NW,64]

  // Workspace layout.
  float* ws     = (float*)d_ws;
  float* h_tic  = ws;                                 // NA*64 floats
  float* h_relm = h_tic + (size_t)NA * 64;            // NA*64 floats
  int2*  edges  = (int2*)(h_relm + (size_t)NA * 64);  // (E_TIC+E_REL) int2
  int*   deg    = (int*)(edges + (size_t)(E_TIC + E_REL));  // NCAT ints
  int*   rp     = deg + NCAT;                         // NCAT ints
  int*   bsum   = rp + NCAT;                          // NBLK ints

  hipMemsetAsync(deg, 0, (size_t)NCAT * 4, stream);

  // L1: word self-GEMM + both degree counts (Bresenham-spread).
  fatA<<<TOT_A, 256, 0, stream>>>(x_w, Wsr, out_w, dst_t, dst_r, deg);

  // L2: prefix scan deg -> rp (row starts).
  scan_block<<<NBLK, 256, 0, stream>>>(deg, rp, bsum);
  scan_bsum<<<1, 256, 0, stream>>>(bsum);
  scan_add<<<(NCAT + 255) / 256, 256, 0, stream>>>(rp, bsum);

  // L3: big acoustic GEMM (3 weight mats) + both CSR fills (Bresenham-spread).
  fatB<<<TOT_B, 256, 0, stream>>>(
      x_ac, Wst, Wnt, Wnr, out_ac, h_tic, h_relm,
      src_t, dst_t, w_t, src_r, dst_r, w_r, rp, edges);

  // L4: both pull aggregations + fused epilogues.
  pull_all<<<(NCAT * 64 + 255) / 256, 256, 0, stream>>>(
      h_tic, h_relm, edges, rp, deg, bt, br, x_w, out_ac, out_w);
}